// Round 3
// baseline (143.681 us; speedup 1.0000x reference)
//
#include <hip/hip_runtime.h>

// GIoU loss, N=4M boxes, [N,4] f32 -> one float4 per box (16B/lane coalesced).
// Memory-bound: 128 MB read/call (~half L3-resident after harness restore).
// R1: 67us — latency-bound, 12 VGPR, no ILP, atomic tail.
// R2: 42.5us — 4x unroll gave ILP but grid=976 starved TLP (occ 31%).
// R3: ILP + TLP: full grid (3907 blocks, 1024 contiguous boxes each, 4
// elems/thread), __launch_bounds__(256,8) keeps <=64 VGPR -> 32 waves/CU.

#define TPB    256
#define CHUNK  (TPB * 4)                 // 1024 boxes per block

__device__ __forceinline__ float giou_term(float4 p, float4 t) {
    float area_p = (p.z - p.x) * (p.w - p.y);
    float area_t = (t.z - t.x) * (t.w - t.y);
    float iw = fmaxf(fminf(p.z, t.z) - fmaxf(p.x, t.x), 0.0f);
    float ih = fmaxf(fminf(p.w, t.w) - fmaxf(p.y, t.y), 0.0f);
    float inter = iw * ih;
    float uni   = area_p + area_t - inter;
    float iou   = inter / uni;
    float cw = fmaxf(p.z, t.z) - fminf(p.x, t.x);
    float ch = fmaxf(p.w, t.w) - fminf(p.y, t.y);
    float area_c = cw * ch;
    return 1.0f - (iou - (area_c - uni) / area_c);
}

__global__ __launch_bounds__(TPB, 8) void giou_main_kernel(
        const float4* __restrict__ pred,
        const float4* __restrict__ targ,
        float* __restrict__ partials,
        int n) {
    const int base = blockIdx.x * CHUNK;
    const int i0   = base + threadIdx.x;
    float sum = 0.0f;

    if (base + CHUNK <= n) {
        // full block: 8 independent float4 loads in flight before any use
        float4 p0 = pred[i0];
        float4 p1 = pred[i0 + TPB];
        float4 p2 = pred[i0 + 2 * TPB];
        float4 p3 = pred[i0 + 3 * TPB];
        float4 t0 = targ[i0];
        float4 t1 = targ[i0 + TPB];
        float4 t2 = targ[i0 + 2 * TPB];
        float4 t3 = targ[i0 + 3 * TPB];
        sum  = giou_term(p0, t0);
        sum += giou_term(p1, t1);
        sum += giou_term(p2, t2);
        sum += giou_term(p3, t3);
    } else {
        // tail block (wave-uniform branch): guarded loads
        #pragma unroll
        for (int k = 0; k < 4; ++k) {
            int i = i0 + k * TPB;
            if (i < n) sum += giou_term(pred[i], targ[i]);
        }
    }

    // wave reduce (wave = 64)
    #pragma unroll
    for (int off = 32; off > 0; off >>= 1)
        sum += __shfl_down(sum, off, 64);

    __shared__ float wave_sums[TPB / 64];
    int lane = threadIdx.x & 63;
    int wid  = threadIdx.x >> 6;
    if (lane == 0) wave_sums[wid] = sum;
    __syncthreads();
    if (threadIdx.x == 0) {
        partials[blockIdx.x] = wave_sums[0] + wave_sums[1]
                             + wave_sums[2] + wave_sums[3];
    }
}

__global__ __launch_bounds__(TPB) void giou_finalize_kernel(
        const float* __restrict__ partials, int nblocks,
        float* __restrict__ out, double inv_n) {
    double s = 0.0;
    for (int i = threadIdx.x; i < nblocks; i += TPB)
        s += (double)partials[i];
    #pragma unroll
    for (int off = 32; off > 0; off >>= 1)
        s += __shfl_down(s, off, 64);
    __shared__ double wave_sums[TPB / 64];
    int lane = threadIdx.x & 63;
    int wid  = threadIdx.x >> 6;
    if (lane == 0) wave_sums[wid] = s;
    __syncthreads();
    if (threadIdx.x == 0) {
        double tot = wave_sums[0] + wave_sums[1] + wave_sums[2] + wave_sums[3];
        *out = (float)(tot * inv_n);
    }
}

extern "C" void kernel_launch(void* const* d_in, const int* in_sizes, int n_in,
                              void* d_out, int out_size, void* d_ws, size_t ws_size,
                              hipStream_t stream) {
    const float4* pred = (const float4*)d_in[0];
    const float4* targ = (const float4*)d_in[1];
    float* out      = (float*)d_out;
    float* partials = (float*)d_ws;          // nblocks floats, all written
    int n = in_sizes[0] / 4;                 // 4,000,000 boxes
    int nblocks = (n + CHUNK - 1) / CHUNK;   // 3907

    giou_main_kernel<<<nblocks, TPB, 0, stream>>>(pred, targ, partials, n);
    giou_finalize_kernel<<<1, TPB, 0, stream>>>(partials, nblocks, out,
                                                1.0 / (double)n);
}